// Round 7
// baseline (210.034 us; speedup 1.0000x reference)
//
#include <hip/hip_runtime.h>
#include <hip/hip_bf16.h>
#include <stdint.h>

#define N_ROWS 16384
#define K_DIM  1024
#define N_OUT  4096

typedef __attribute__((ext_vector_type(8))) short short8;
typedef __attribute__((ext_vector_type(4))) float f32x4;
typedef __attribute__((ext_vector_type(4))) __bf16 bf16x4;

// ---------------- fp32 -> bf16 convert (dense, for W) -------------------------
__global__ void cvt_kernel(const float* __restrict__ in, __bf16* __restrict__ out, int n4) {
    int stride = gridDim.x * blockDim.x;
    for (int i = blockIdx.x * blockDim.x + threadIdx.x; i < n4; i += stride) {
        float4 v = reinterpret_cast<const float4*>(in)[i];
        bf16x4 o;
        o[0] = (__bf16)v.x; o[1] = (__bf16)v.y; o[2] = (__bf16)v.z; o[3] = (__bf16)v.w;
        reinterpret_cast<bf16x4*>(out)[i] = o;
    }
}

// ---------------- gather + convert: xb[i] = bf16(x[idx[i]]), i < cnt ----------
__global__ __launch_bounds__(256) void cvt_gather_kernel(
    const float* __restrict__ x, const int* __restrict__ idx,
    const int* __restrict__ count, __bf16* __restrict__ xb) {
    const int cnt = count[0];
    const int t = threadIdx.x;                   // 256 threads = 256 float4/row
    for (int j = blockIdx.x; j < cnt; j += gridDim.x) {
        const int row = idx[j];
        float4 v = reinterpret_cast<const float4*>(x + (size_t)row * K_DIM)[t];
        bf16x4 o;
        o[0] = (__bf16)v.x; o[1] = (__bf16)v.y; o[2] = (__bf16)v.z; o[3] = (__bf16)v.w;
        reinterpret_cast<bf16x4*>(xb + (size_t)j * K_DIM)[t] = o;
    }
}

// ---------------- mask compaction: idx (active rows), zidx (masked), count ----
__global__ __launch_bounds__(1024) void scan_kernel(const int* __restrict__ amask,
                                                    int* __restrict__ idx,
                                                    int* __restrict__ zidx,
                                                    int* __restrict__ count) {
    __shared__ int sc[1024];
    const int t = threadIdx.x;
    const int base = t * 16;                     // 16 rows per thread
    int mk[16];
#pragma unroll
    for (int g = 0; g < 4; ++g) {
        int4 m4 = reinterpret_cast<const int4*>(amask + base)[g];
        mk[g*4+0] = m4.x; mk[g*4+1] = m4.y; mk[g*4+2] = m4.z; mk[g*4+3] = m4.w;
    }
    int c = 0;
#pragma unroll
    for (int i = 0; i < 16; ++i) c += (mk[i] != 0) ? 1 : 0;
    int v = c;
    sc[t] = v;
    __syncthreads();
    for (int off = 1; off < 1024; off <<= 1) {   // Hillis-Steele inclusive scan
        int u = (t >= off) ? sc[t - off] : 0;
        __syncthreads();
        v += u; sc[t] = v;
        __syncthreads();
    }
    int b  = v - c;
    int zb = base - b;
#pragma unroll
    for (int i = 0; i < 16; ++i) {
        int r = base + i;
        if (mk[i] != 0) idx[b++] = r; else zidx[zb++] = r;
    }
    if (t == 1023) count[0] = v;
}

// ---------------- compacted 128x128 m97-structure bf16 MFMA GEMM --------------
// The verified regime: 128^2 tile, BK=32, 4 waves (2x2), 16 KB LDS single
// buffer, 2 syncthreads per K-tile, global_load_lds w16. VGPR ~84 -> ~6
// blocks/CU: cross-block overlap hides the barrier drain (m114/m103).
// Frag-linear LDS (R2-proven, 0 bank conflicts): frag f of a tile at f*1KB,
// lane l at l*16B; staging source pre-permuted to match.
// Grid = 4096 blocks: heavy blocks (aT*32) compute; the rest zero-fill
// masked rows in fine grain (interleaves with compute, no tail round).

#define GLL(SRC, DSTOFF)                                                       \
    __builtin_amdgcn_global_load_lds(                                          \
        (const __attribute__((address_space(1))) void*)(SRC),                  \
        (__attribute__((address_space(3))) void*)(ldsc + (DSTOFF)), 16, 0, 0)

__global__ __launch_bounds__(256) void gemm_kernel(
    const __bf16* __restrict__ A,      // compacted active rows
    const __bf16* __restrict__ B,
    const float*  __restrict__ bias,
    const int*    __restrict__ idx,
    const int*    __restrict__ zidx,
    const int*    __restrict__ count,
    float*        __restrict__ out)
{
    __shared__ short lds_all[8192];    // 16 KB: A 8 KB @0, B 8 KB @8192B

    const int t  = threadIdx.x;
    const int l  = t & 63;
    const int w  = t >> 6;             // wave 0..3
    const int wm = w >> 1;             // 0..1 (row half: 64 rows)
    const int wn = w & 1;              // 0..1 (col half: 64 cols)

    const int cnt = count[0];
    const int aT  = (cnt + 127) >> 7;  // active row-tiles of 128 (0..128)
    const int q   = (aT + 7) >> 3;     // heavy row-tiles per XCD (ceil)

    const int bid = blockIdx.x;        // 0..4095
    const int xcd = bid & 7;
    const int c   = bid >> 3;          // 0..511
    const int pre = min(xcd * q, aT);  // heavy row-tiles before this XCD
    int own = aT - pre; if (own > q) own = q; if (own < 0) own = 0;

    if (c >= own * 32) {
        // ---- zero-fill role: trivial rank -> (col-tile, masked-row slice) ----
        const int tr  = (512 * xcd - 32 * pre) + (c - 32 * own);
        const int tnt = tr & 31;           // col-tile 0..31
        const int zsl = tr >> 5;           // slice 0 .. (128-aT-1)
        const int zt  = 128 - aT;          // >=1 whenever trivial blocks exist
        const int nz  = N_ROWS - cnt;
        const int rpz = (nz + zt - 1) / zt;
        const int lo  = zsl * rpz;
        const int hi0 = lo + rpz;
        const int hi  = hi0 < nz ? hi0 : nz;
        const int n0z = tnt * 128;
        const float2 zf = make_float2(0.f, 0.f);
        for (int i = lo + w; i < hi; i += 4) {
            const int row = zidx[i];
            float2* p = reinterpret_cast<float2*>(out + (size_t)row * N_OUT + n0z);
            p[l] = zf;                     // 64 lanes x 8B = full 128-col stripe
        }
        return;
    }

    // ---- heavy role: tm local-fast within this XCD's contiguous chunk ----
    const int tm = pre + (c % own);
    const int tn = c / own;
    const int m0 = tm * 128;               // base in COMPACTED row space
    const int n0 = tn * 128;

    // Frag-linear staging: pass p (0,1), thread t stages byte p*4096 + t*16 =
    // frag (p*4 + t/64), lane (t&63) -> row = frag*16 + (l&15), k8 = ((t>>4)&3)*8.
    const int rowoff = ((t >> 6) << 4) + (t & 15);   // pass-0 row
    const int klane  = ((t >> 4) & 3) * 8;
    const __bf16* pA0 = A + (size_t)(m0 + rowoff) * K_DIM + klane;
    const __bf16* pA1 = pA0 + (size_t)64 * K_DIM;    // pass-1 rows (+64)
    const __bf16* pB0 = B + (size_t)(n0 + rowoff) * K_DIM + klane;
    const __bf16* pB1 = pB0 + (size_t)64 * K_DIM;
    char* ldsc = (char*)lds_all;

    f32x4 acc[4][4] = {};

    for (int k0 = 0; k0 < K_DIM; k0 += 32) {
        GLL(pA0 + k0, t * 16);             // A pass 0: frags 0-3
        GLL(pA1 + k0, 4096 + t * 16);      // A pass 1: frags 4-7
        GLL(pB0 + k0, 8192 + t * 16);      // B pass 0
        GLL(pB1 + k0, 12288 + t * 16);     // B pass 1
        __syncthreads();                    // drains vmcnt before barrier

        short8 af[4], bf[4];
#pragma unroll
        for (int mi = 0; mi < 4; ++mi)
            af[mi] = *(const short8*)(lds_all + (wm*4 + mi)*512 + l*8);
#pragma unroll
        for (int ni = 0; ni < 4; ++ni)
            bf[ni] = *(const short8*)(lds_all + 4096 + (wn*4 + ni)*512 + l*8);

#pragma unroll
        for (int mi = 0; mi < 4; ++mi)
#pragma unroll
            for (int ni = 0; ni < 4; ++ni)
                acc[mi][ni] = __builtin_amdgcn_mfma_f32_16x16x32_bf16(
                    af[mi], bf[ni], acc[mi][ni], 0, 0, 0);
        __syncthreads();
    }

    // Epilogue: bias add, scatter to original rows, guard padded slots.
    const int lr = l & 15;
    const int lq = l >> 4;
    float bv[4];
#pragma unroll
    for (int ni = 0; ni < 4; ++ni) bv[ni] = bias[n0 + wn*64 + ni*16 + lr];

#pragma unroll
    for (int mi = 0; mi < 4; ++mi) {
        const int slot0 = m0 + wm*64 + mi*16 + lq*4;
        int rowid[4]; bool val[4];
#pragma unroll
        for (int r = 0; r < 4; ++r) {
            const int s = slot0 + r;
            val[r] = (s < cnt);
            rowid[r] = val[r] ? idx[s] : 0;
        }
#pragma unroll
        for (int ni = 0; ni < 4; ++ni) {
            const int cc = n0 + wn*64 + ni*16 + lr;
#pragma unroll
            for (int r = 0; r < 4; ++r)
                if (val[r]) out[(size_t)rowid[r] * N_OUT + cc] = acc[mi][ni][r] + bv[ni];
        }
    }
}

// ---------------- naive fp32 fallback (only if ws too small) ------------------
__global__ void naive_kernel(const float* __restrict__ x, const float* __restrict__ W,
                             const float* __restrict__ bias, const int* __restrict__ amask,
                             float* __restrict__ out) {
    int c = blockIdx.x * blockDim.x + threadIdx.x;
    int r = blockIdx.y;
    if (c >= N_OUT) return;
    if (amask[r] == 0) { out[(size_t)r * N_OUT + c] = 0.0f; return; }
    const float* xr = x + (size_t)r * K_DIM;
    const float* wr = W + (size_t)c * K_DIM;
    float s = 0.0f;
    for (int k = 0; k < K_DIM; ++k) s += xr[k] * wr[k];
    out[(size_t)r * N_OUT + c] = s + bias[c];
}

extern "C" void kernel_launch(void* const* d_in, const int* in_sizes, int n_in,
                              void* d_out, int out_size, void* d_ws, size_t ws_size,
                              hipStream_t stream) {
    const float* x     = (const float*)d_in[0];
    const int*   amask = (const int*)d_in[1];
    const float* W     = (const float*)d_in[2];
    const float* bias  = (const float*)d_in[3];
    float*       out   = (float*)d_out;

    const size_t xb_bytes = (size_t)N_ROWS * K_DIM * 2;   // 32 MB
    const size_t wb_bytes = (size_t)N_OUT  * K_DIM * 2;   //  8 MB
    const size_t idx_bytes = (size_t)N_ROWS * 4;          // 64 KB
    const size_t need = xb_bytes + wb_bytes + 2 * idx_bytes + 256;

    if (ws_size < need) {
        dim3 g((N_OUT + 255) / 256, N_ROWS);
        naive_kernel<<<g, 256, 0, stream>>>(x, W, bias, amask, out);
        return;
    }

    __bf16* xb   = (__bf16*)d_ws;
    __bf16* wb   = (__bf16*)((char*)d_ws + xb_bytes);
    int*    idx  = (int*)((char*)d_ws + xb_bytes + wb_bytes);
    int*    zidx = idx + N_ROWS;
    int*    cnt  = zidx + N_ROWS;

    scan_kernel<<<1, 1024, 0, stream>>>(amask, idx, zidx, cnt);
    cvt_gather_kernel<<<2048, 256, 0, stream>>>(x, idx, cnt, xb);
    cvt_kernel<<<1024, 256, 0, stream>>>(W, wb, N_OUT * K_DIM / 4);

    gemm_kernel<<<4096, 256, 0, stream>>>(xb, wb, bias, idx, zidx, cnt, out);
}

// Round 8
// 182.587 us; speedup vs baseline: 1.1503x; 1.1503x over previous
//
#include <hip/hip_runtime.h>
#include <hip/hip_bf16.h>
#include <stdint.h>

#define N_ROWS 16384
#define K_DIM  1024
#define N_OUT  4096

typedef __attribute__((ext_vector_type(8))) short short8;
typedef __attribute__((ext_vector_type(4))) float f32x4;
typedef __attribute__((ext_vector_type(4))) __bf16 bf16x4;

// ---------------- fp32 -> bf16 convert (dense, for W) -------------------------
__global__ void cvt_kernel(const float* __restrict__ in, __bf16* __restrict__ out, int n4) {
    int stride = gridDim.x * blockDim.x;
    for (int i = blockIdx.x * blockDim.x + threadIdx.x; i < n4; i += stride) {
        float4 v = reinterpret_cast<const float4*>(in)[i];
        bf16x4 o;
        o[0] = (__bf16)v.x; o[1] = (__bf16)v.y; o[2] = (__bf16)v.z; o[3] = (__bf16)v.w;
        reinterpret_cast<bf16x4*>(out)[i] = o;
    }
}

// ---------------- gather + convert: xb[i] = bf16(x[idx[i]]), i < cnt ----------
__global__ __launch_bounds__(256) void cvt_gather_kernel(
    const float* __restrict__ x, const int* __restrict__ idx,
    const int* __restrict__ count, __bf16* __restrict__ xb) {
    const int cnt = count[0];
    const int t = threadIdx.x;                   // 256 threads = 256 float4/row
    for (int j = blockIdx.x; j < cnt; j += gridDim.x) {
        const int row = idx[j];
        float4 v = reinterpret_cast<const float4*>(x + (size_t)row * K_DIM)[t];
        bf16x4 o;
        o[0] = (__bf16)v.x; o[1] = (__bf16)v.y; o[2] = (__bf16)v.z; o[3] = (__bf16)v.w;
        reinterpret_cast<bf16x4*>(xb + (size_t)j * K_DIM)[t] = o;
    }
}

// ---------------- mask compaction: idx (active rows), zidx (masked), count ----
__global__ __launch_bounds__(1024) void scan_kernel(const int* __restrict__ amask,
                                                    int* __restrict__ idx,
                                                    int* __restrict__ zidx,
                                                    int* __restrict__ count) {
    __shared__ int sc[1024];
    const int t = threadIdx.x;
    const int base = t * 16;                     // 16 rows per thread
    int mk[16];
#pragma unroll
    for (int g = 0; g < 4; ++g) {
        int4 m4 = reinterpret_cast<const int4*>(amask + base)[g];
        mk[g*4+0] = m4.x; mk[g*4+1] = m4.y; mk[g*4+2] = m4.z; mk[g*4+3] = m4.w;
    }
    int c = 0;
#pragma unroll
    for (int i = 0; i < 16; ++i) c += (mk[i] != 0) ? 1 : 0;
    int v = c;
    sc[t] = v;
    __syncthreads();
    for (int off = 1; off < 1024; off <<= 1) {   // Hillis-Steele inclusive scan
        int u = (t >= off) ? sc[t - off] : 0;
        __syncthreads();
        v += u; sc[t] = v;
        __syncthreads();
    }
    int b  = v - c;
    int zb = base - b;
#pragma unroll
    for (int i = 0; i < 16; ++i) {
        int r = base + i;
        if (mk[i] != 0) idx[b++] = r; else zidx[zb++] = r;
    }
    if (t == 1023) count[0] = v;
}

// ---------------- compacted 128x128 m97-structure bf16 MFMA GEMM --------------
// STAGING COALESCING RESTORED (R1 pattern): LDS is row-major [row][32] bf16,
// dest = t*16 linear; global source row = t>>2, k8 = (t&3)*8 -> lane groups
// of 4 read consecutive 16B of one row (64B line coalescing, 16 lines/wave)
// instead of R2-R7's 64-line 16B-granule gather (4x L2 request amplification).
// 2-way-ish LDS bank conflicts from this layout are free (m136; R1 proved it).
// Heavy/trivial blocks INTERLEAVED in dispatch order (R4's measured +6%):
// heavy iff ((c+1)*h)>>9 > (c*h)>>9 with h = own*32 heavy blocks per XCD.

#define GLL(SRC, DSTOFF)                                                       \
    __builtin_amdgcn_global_load_lds(                                          \
        (const __attribute__((address_space(1))) void*)(SRC),                  \
        (__attribute__((address_space(3))) void*)(ldsc + (DSTOFF)), 16, 0, 0)

__global__ __launch_bounds__(256) void gemm_kernel(
    const __bf16* __restrict__ A,      // compacted active rows
    const __bf16* __restrict__ B,
    const float*  __restrict__ bias,
    const int*    __restrict__ idx,
    const int*    __restrict__ zidx,
    const int*    __restrict__ count,
    float*        __restrict__ out)
{
    __shared__ short lds_all[8192];    // 16 KB: A [128][32] @0, B [128][32] @8192B

    const int t  = threadIdx.x;
    const int l  = t & 63;
    const int w  = t >> 6;             // wave 0..3
    const int wm = w >> 1;             // 0..1 (row half: 64 rows)
    const int wn = w & 1;              // 0..1 (col half: 64 cols)

    const int cnt = count[0];
    const int aT  = (cnt + 127) >> 7;  // active row-tiles of 128 (0..128)
    const int q   = (aT + 7) >> 3;     // heavy row-tiles per XCD (ceil)

    const int bid = blockIdx.x;        // 0..4095
    const int xcd = bid & 7;
    const int c   = bid >> 3;          // 0..511
    const int pre = min(xcd * q, aT);  // heavy row-tiles before this XCD
    int own = aT - pre; if (own > q) own = q; if (own < 0) own = 0;
    const int h   = own * 32;          // heavy blocks in this XCD (0..512)

    // Balanced interleave of heavy/trivial through dispatch order.
    const int hb   = (c * h) >> 9;
    const bool hvy = (((c + 1) * h) >> 9) > hb;

    if (!hvy) {
        // ---- zero-fill role: global trivial rank -> (col-tile, row slice) ----
        const int trank = c - hb;              // local trivial rank 0..511-h
        const int tr  = (512 * xcd - 32 * pre) + trank;
        const int tnt = tr & 31;               // col-tile 0..31 (128 cols)
        const int zsl = tr >> 5;               // slice 0 .. (128-aT-1)
        const int zt  = 128 - aT;              // >=1 whenever trivial exist
        const int nz  = N_ROWS - cnt;
        const int rpz = (nz + zt - 1) / zt;
        const int lo  = zsl * rpz;
        const int hi0 = lo + rpz;
        const int hi  = hi0 < nz ? hi0 : nz;
        const int n0z = tnt * 128;
        const float2 zf = make_float2(0.f, 0.f);
        for (int i = lo + w; i < hi; i += 4) {
            const int row = zidx[i];
            float2* p = reinterpret_cast<float2*>(out + (size_t)row * N_OUT + n0z);
            p[l] = zf;                         // 64 lanes x 8B = 128-col stripe
        }
        return;
    }

    // ---- heavy role: tm local-fast within this XCD's contiguous chunk ----
    const int tm = pre + (hb % own);
    const int tn = hb / own;
    const int m0 = tm * 128;               // base in COMPACTED row space
    const int n0 = tn * 128;

    // R1-style coalesced staging: thread t stages row (t>>2), k8 = (t&3)*8.
    const int srow = t >> 2;
    const int sk8  = (t & 3) * 8;
    const __bf16* pA0 = A + (size_t)(m0 + srow) * K_DIM + sk8;
    const __bf16* pA1 = pA0 + (size_t)64 * K_DIM;
    const __bf16* pB0 = B + (size_t)(n0 + srow) * K_DIM + sk8;
    const __bf16* pB1 = pB0 + (size_t)64 * K_DIM;
    char* ldsc = (char*)lds_all;

    const int lr = l & 15;                 // fragment row lane index
    const int lk = (l >> 4) * 8;           // k-run element offset

    f32x4 acc[4][4] = {};

    for (int k0 = 0; k0 < K_DIM; k0 += 32) {
        GLL(pA0 + k0, t * 16);             // A rows 0-63
        GLL(pA1 + k0, 4096 + t * 16);      // A rows 64-127
        GLL(pB0 + k0, 8192 + t * 16);      // B rows 0-63
        GLL(pB1 + k0, 12288 + t * 16);     // B rows 64-127
        __syncthreads();                    // drains vmcnt before barrier

        short8 af[4], bf[4];
#pragma unroll
        for (int mi = 0; mi < 4; ++mi)
            af[mi] = *(const short8*)(lds_all + (wm*64 + mi*16 + lr)*32 + lk);
#pragma unroll
        for (int ni = 0; ni < 4; ++ni)
            bf[ni] = *(const short8*)(lds_all + 4096 + (wn*64 + ni*16 + lr)*32 + lk);

#pragma unroll
        for (int mi = 0; mi < 4; ++mi)
#pragma unroll
            for (int ni = 0; ni < 4; ++ni)
                acc[mi][ni] = __builtin_amdgcn_mfma_f32_16x16x32_bf16(
                    af[mi], bf[ni], acc[mi][ni], 0, 0, 0);
        __syncthreads();
    }

    // Epilogue: bias add, scatter to original rows, guard padded slots.
    const int lq = l >> 4;
    float bv[4];
#pragma unroll
    for (int ni = 0; ni < 4; ++ni) bv[ni] = bias[n0 + wn*64 + ni*16 + lr];

#pragma unroll
    for (int mi = 0; mi < 4; ++mi) {
        const int slot0 = m0 + wm*64 + mi*16 + lq*4;
        int rowid[4]; bool val[4];
#pragma unroll
        for (int r = 0; r < 4; ++r) {
            const int s = slot0 + r;
            val[r] = (s < cnt);
            rowid[r] = val[r] ? idx[s] : 0;
        }
#pragma unroll
        for (int ni = 0; ni < 4; ++ni) {
            const int cc = n0 + wn*64 + ni*16 + lr;
#pragma unroll
            for (int r = 0; r < 4; ++r)
                if (val[r]) out[(size_t)rowid[r] * N_OUT + cc] = acc[mi][ni][r] + bv[ni];
        }
    }
}

// ---------------- naive fp32 fallback (only if ws too small) ------------------
__global__ void naive_kernel(const float* __restrict__ x, const float* __restrict__ W,
                             const float* __restrict__ bias, const int* __restrict__ amask,
                             float* __restrict__ out) {
    int c = blockIdx.x * blockDim.x + threadIdx.x;
    int r = blockIdx.y;
    if (c >= N_OUT) return;
    if (amask[r] == 0) { out[(size_t)r * N_OUT + c] = 0.0f; return; }
    const float* xr = x + (size_t)r * K_DIM;
    const float* wr = W + (size_t)c * K_DIM;
    float s = 0.0f;
    for (int k = 0; k < K_DIM; ++k) s += xr[k] * wr[k];
    out[(size_t)r * N_OUT + c] = s + bias[c];
}

extern "C" void kernel_launch(void* const* d_in, const int* in_sizes, int n_in,
                              void* d_out, int out_size, void* d_ws, size_t ws_size,
                              hipStream_t stream) {
    const float* x     = (const float*)d_in[0];
    const int*   amask = (const int*)d_in[1];
    const float* W     = (const float*)d_in[2];
    const float* bias  = (const float*)d_in[3];
    float*       out   = (float*)d_out;

    const size_t xb_bytes = (size_t)N_ROWS * K_DIM * 2;   // 32 MB
    const size_t wb_bytes = (size_t)N_OUT  * K_DIM * 2;   //  8 MB
    const size_t idx_bytes = (size_t)N_ROWS * 4;          // 64 KB
    const size_t need = xb_bytes + wb_bytes + 2 * idx_bytes + 256;

    if (ws_size < need) {
        dim3 g((N_OUT + 255) / 256, N_ROWS);
        naive_kernel<<<g, 256, 0, stream>>>(x, W, bias, amask, out);
        return;
    }

    __bf16* xb   = (__bf16*)d_ws;
    __bf16* wb   = (__bf16*)((char*)d_ws + xb_bytes);
    int*    idx  = (int*)((char*)d_ws + xb_bytes + wb_bytes);
    int*    zidx = idx + N_ROWS;
    int*    cnt  = zidx + N_ROWS;

    scan_kernel<<<1, 1024, 0, stream>>>(amask, idx, zidx, cnt);
    cvt_gather_kernel<<<2048, 256, 0, stream>>>(x, idx, cnt, xb);
    cvt_kernel<<<1024, 256, 0, stream>>>(W, wb, N_OUT * K_DIM / 4);

    gemm_kernel<<<4096, 256, 0, stream>>>(xb, wb, bias, idx, zidx, cnt, out);
}

// Round 9
// 174.967 us; speedup vs baseline: 1.2004x; 1.0436x over previous
//
#include <hip/hip_runtime.h>
#include <hip/hip_bf16.h>
#include <stdint.h>

#define N_ROWS 16384
#define K_DIM  1024
#define N_OUT  4096

typedef __attribute__((ext_vector_type(8))) short short8;
typedef __attribute__((ext_vector_type(4))) float f32x4;
typedef __attribute__((ext_vector_type(4))) __bf16 bf16x4;

// ---------------- prep: block 0 = mask scan, blocks 1..1024 = cvt W -----------
__global__ __launch_bounds__(1024) void prep_kernel(
    const int*   __restrict__ amask,
    const float* __restrict__ W,
    int* __restrict__ idx, int* __restrict__ zidx, int* __restrict__ count,
    __bf16* __restrict__ wb)
{
    const int t = threadIdx.x;
    if (blockIdx.x != 0) {
        // ---- cvt W: exactly one float4 per thread ----
        const int i = (blockIdx.x - 1) * 1024 + t;   // < 1,048,576
        float4 v = reinterpret_cast<const float4*>(W)[i];
        bf16x4 o;
        o[0] = (__bf16)v.x; o[1] = (__bf16)v.y; o[2] = (__bf16)v.z; o[3] = (__bf16)v.w;
        reinterpret_cast<bf16x4*>(wb)[i] = o;
        return;
    }
    // ---- mask compaction scan (1024 threads, 16 rows each) ----
    __shared__ int sc[1024];
    const int base = t * 16;
    int mk[16];
#pragma unroll
    for (int g = 0; g < 4; ++g) {
        int4 m4 = reinterpret_cast<const int4*>(amask + base)[g];
        mk[g*4+0] = m4.x; mk[g*4+1] = m4.y; mk[g*4+2] = m4.z; mk[g*4+3] = m4.w;
    }
    int c = 0;
#pragma unroll
    for (int i = 0; i < 16; ++i) c += (mk[i] != 0) ? 1 : 0;
    int v = c;
    sc[t] = v;
    __syncthreads();
    for (int off = 1; off < 1024; off <<= 1) {       // Hillis-Steele scan
        int u = (t >= off) ? sc[t - off] : 0;
        __syncthreads();
        v += u; sc[t] = v;
        __syncthreads();
    }
    int b  = v - c;
    int zb = base - b;
#pragma unroll
    for (int i = 0; i < 16; ++i) {
        int r = base + i;
        if (mk[i] != 0) idx[b++] = r; else zidx[zb++] = r;
    }
    if (t == 1023) count[0] = v;
}

// ---------------- gather + convert: xb[i] = bf16(x[idx[i]]), i < cnt ----------
__global__ __launch_bounds__(256) void cvt_gather_kernel(
    const float* __restrict__ x, const int* __restrict__ idx,
    const int* __restrict__ count, __bf16* __restrict__ xb) {
    const int cnt = count[0];
    const int t = threadIdx.x;                   // 256 threads = 256 float4/row
    for (int j = blockIdx.x; j < cnt; j += gridDim.x) {
        const int row = idx[j];
        float4 v = reinterpret_cast<const float4*>(x + (size_t)row * K_DIM)[t];
        bf16x4 o;
        o[0] = (__bf16)v.x; o[1] = (__bf16)v.y; o[2] = (__bf16)v.z; o[3] = (__bf16)v.w;
        reinterpret_cast<bf16x4*>(xb + (size_t)j * K_DIM)[t] = o;
    }
}

// ---------------- compacted 128x128 m97-structure bf16 MFMA GEMM --------------
// Heavy path identical to R8 (best measured). Zero-fill REWORKED: trivial
// blocks take a GLOBAL rank, each owns ~4 masked rows and writes them as
// FULL 16KB rows with float4 (1KB per wave-instr, contiguous) instead of
// R8's scattered 512B 128-col stripes — same bytes, maximal HBM locality.

#define GLL(SRC, DSTOFF)                                                       \
    __builtin_amdgcn_global_load_lds(                                          \
        (const __attribute__((address_space(1))) void*)(SRC),                  \
        (__attribute__((address_space(3))) void*)(ldsc + (DSTOFF)), 16, 0, 0)

__global__ __launch_bounds__(256) void gemm_kernel(
    const __bf16* __restrict__ A,      // compacted active rows
    const __bf16* __restrict__ B,
    const float*  __restrict__ bias,
    const int*    __restrict__ idx,
    const int*    __restrict__ zidx,
    const int*    __restrict__ count,
    float*        __restrict__ out)
{
    __shared__ short lds_all[8192];    // 16 KB: A [128][32] @0, B [128][32] @8192B

    const int t  = threadIdx.x;
    const int l  = t & 63;
    const int w  = t >> 6;             // wave 0..3
    const int wm = w >> 1;             // 0..1 (row half: 64 rows)
    const int wn = w & 1;              // 0..1 (col half: 64 cols)

    const int cnt = count[0];
    const int aT  = (cnt + 127) >> 7;  // active row-tiles of 128 (0..128)
    const int q   = (aT + 7) >> 3;     // heavy row-tiles per XCD (ceil)

    const int bid = blockIdx.x;        // 0..4095
    const int xcd = bid & 7;
    const int c   = bid >> 3;          // 0..511
    const int pre = min(xcd * q, aT);  // heavy row-tiles before this XCD
    int own = aT - pre; if (own > q) own = q; if (own < 0) own = 0;
    const int h   = own * 32;          // heavy blocks in this XCD (0..512)

    // Balanced interleave of heavy/trivial through dispatch order.
    const int hb   = (c * h) >> 9;
    const bool hvy = (((c + 1) * h) >> 9) > hb;

    if (!hvy) {
        // ---- zero-fill role: global rank -> ~4 FULL masked rows, float4 ----
        const int tr    = (512 * xcd - 32 * pre) + (c - hb);  // global trivial rank
        const int ntriv = 4096 - aT * 32;                     // >= 1 here
        const int nz    = N_ROWS - cnt;
        const int rpz   = (nz + ntriv - 1) / ntriv;
        const int lo    = tr * rpz;
        const int hi0   = lo + rpz;
        const int hi    = hi0 < nz ? hi0 : nz;
        const float4 zf = make_float4(0.f, 0.f, 0.f, 0.f);
        for (int i = lo + w; i < hi; i += 4) {                // wave per row
            const int row = zidx[i];
            float4* p = reinterpret_cast<float4*>(out + (size_t)row * N_OUT);
#pragma unroll
            for (int u = 0; u < 16; ++u)                      // 16 x 1KB = 16KB row
                p[u * 64 + l] = zf;
        }
        return;
    }

    // ---- heavy role: tm local-fast within this XCD's contiguous chunk ----
    const int tm = pre + (hb % own);
    const int tn = hb / own;
    const int m0 = tm * 128;               // base in COMPACTED row space
    const int n0 = tn * 128;

    // R1-style coalesced staging: thread t stages row (t>>2), k8 = (t&3)*8.
    const int srow = t >> 2;
    const int sk8  = (t & 3) * 8;
    const __bf16* pA0 = A + (size_t)(m0 + srow) * K_DIM + sk8;
    const __bf16* pA1 = pA0 + (size_t)64 * K_DIM;
    const __bf16* pB0 = B + (size_t)(n0 + srow) * K_DIM + sk8;
    const __bf16* pB1 = pB0 + (size_t)64 * K_DIM;
    char* ldsc = (char*)lds_all;

    const int lr = l & 15;                 // fragment row lane index
    const int lk = (l >> 4) * 8;           // k-run element offset

    f32x4 acc[4][4] = {};

    for (int k0 = 0; k0 < K_DIM; k0 += 32) {
        GLL(pA0 + k0, t * 16);             // A rows 0-63
        GLL(pA1 + k0, 4096 + t * 16);      // A rows 64-127
        GLL(pB0 + k0, 8192 + t * 16);      // B rows 0-63
        GLL(pB1 + k0, 12288 + t * 16);     // B rows 64-127
        __syncthreads();                    // drains vmcnt before barrier

        short8 af[4], bf[4];
#pragma unroll
        for (int mi = 0; mi < 4; ++mi)
            af[mi] = *(const short8*)(lds_all + (wm*64 + mi*16 + lr)*32 + lk);
#pragma unroll
        for (int ni = 0; ni < 4; ++ni)
            bf[ni] = *(const short8*)(lds_all + 4096 + (wn*64 + ni*16 + lr)*32 + lk);

#pragma unroll
        for (int mi = 0; mi < 4; ++mi)
#pragma unroll
            for (int ni = 0; ni < 4; ++ni)
                acc[mi][ni] = __builtin_amdgcn_mfma_f32_16x16x32_bf16(
                    af[mi], bf[ni], acc[mi][ni], 0, 0, 0);
        __syncthreads();
    }

    // Epilogue: bias add, scatter to original rows, guard padded slots.
    const int lq = l >> 4;
    float bv[4];
#pragma unroll
    for (int ni = 0; ni < 4; ++ni) bv[ni] = bias[n0 + wn*64 + ni*16 + lr];

#pragma unroll
    for (int mi = 0; mi < 4; ++mi) {
        const int slot0 = m0 + wm*64 + mi*16 + lq*4;
        int rowid[4]; bool val[4];
#pragma unroll
        for (int r = 0; r < 4; ++r) {
            const int s = slot0 + r;
            val[r] = (s < cnt);
            rowid[r] = val[r] ? idx[s] : 0;
        }
#pragma unroll
        for (int ni = 0; ni < 4; ++ni) {
            const int cc = n0 + wn*64 + ni*16 + lr;
#pragma unroll
            for (int r = 0; r < 4; ++r)
                if (val[r]) out[(size_t)rowid[r] * N_OUT + cc] = acc[mi][ni][r] + bv[ni];
        }
    }
}

// ---------------- naive fp32 fallback (only if ws too small) ------------------
__global__ void naive_kernel(const float* __restrict__ x, const float* __restrict__ W,
                             const float* __restrict__ bias, const int* __restrict__ amask,
                             float* __restrict__ out) {
    int c = blockIdx.x * blockDim.x + threadIdx.x;
    int r = blockIdx.y;
    if (c >= N_OUT) return;
    if (amask[r] == 0) { out[(size_t)r * N_OUT + c] = 0.0f; return; }
    const float* xr = x + (size_t)r * K_DIM;
    const float* wr = W + (size_t)c * K_DIM;
    float s = 0.0f;
    for (int k = 0; k < K_DIM; ++k) s += xr[k] * wr[k];
    out[(size_t)r * N_OUT + c] = s + bias[c];
}

extern "C" void kernel_launch(void* const* d_in, const int* in_sizes, int n_in,
                              void* d_out, int out_size, void* d_ws, size_t ws_size,
                              hipStream_t stream) {
    const float* x     = (const float*)d_in[0];
    const int*   amask = (const int*)d_in[1];
    const float* W     = (const float*)d_in[2];
    const float* bias  = (const float*)d_in[3];
    float*       out   = (float*)d_out;

    const size_t xb_bytes = (size_t)N_ROWS * K_DIM * 2;   // 32 MB
    const size_t wb_bytes = (size_t)N_OUT  * K_DIM * 2;   //  8 MB
    const size_t idx_bytes = (size_t)N_ROWS * 4;          // 64 KB
    const size_t need = xb_bytes + wb_bytes + 2 * idx_bytes + 256;

    if (ws_size < need) {
        dim3 g((N_OUT + 255) / 256, N_ROWS);
        naive_kernel<<<g, 256, 0, stream>>>(x, W, bias, amask, out);
        return;
    }

    __bf16* xb   = (__bf16*)d_ws;
    __bf16* wb   = (__bf16*)((char*)d_ws + xb_bytes);
    int*    idx  = (int*)((char*)d_ws + xb_bytes + wb_bytes);
    int*    zidx = idx + N_ROWS;
    int*    cnt  = zidx + N_ROWS;

    prep_kernel<<<1025, 1024, 0, stream>>>(amask, W, idx, zidx, cnt, wb);
    cvt_gather_kernel<<<2048, 256, 0, stream>>>(x, idx, cnt, xb);

    gemm_kernel<<<4096, 256, 0, stream>>>(xb, wb, bias, idx, zidx, cnt, out);
}

// Round 10
// 154.841 us; speedup vs baseline: 1.3564x; 1.1300x over previous
//
#include <hip/hip_runtime.h>
#include <hip/hip_bf16.h>
#include <stdint.h>

#define N_ROWS 16384
#define K_DIM  1024
#define N_OUT  4096

typedef __attribute__((ext_vector_type(8))) short short8;
typedef __attribute__((ext_vector_type(4))) float f32x4;
typedef __attribute__((ext_vector_type(4))) __bf16 bf16x4;

// ---------------- prep: block 0 = mask scan, blocks 1..1024 = cvt W -----------
__global__ __launch_bounds__(1024) void prep_kernel(
    const int*   __restrict__ amask,
    const float* __restrict__ W,
    int* __restrict__ idx, int* __restrict__ zidx, int* __restrict__ count,
    __bf16* __restrict__ wb)
{
    const int t = threadIdx.x;
    if (blockIdx.x != 0) {
        const int i = (blockIdx.x - 1) * 1024 + t;   // < 1,048,576
        float4 v = reinterpret_cast<const float4*>(W)[i];
        bf16x4 o;
        o[0] = (__bf16)v.x; o[1] = (__bf16)v.y; o[2] = (__bf16)v.z; o[3] = (__bf16)v.w;
        reinterpret_cast<bf16x4*>(wb)[i] = o;
        return;
    }
    __shared__ int sc[1024];
    const int base = t * 16;
    int mk[16];
#pragma unroll
    for (int g = 0; g < 4; ++g) {
        int4 m4 = reinterpret_cast<const int4*>(amask + base)[g];
        mk[g*4+0] = m4.x; mk[g*4+1] = m4.y; mk[g*4+2] = m4.z; mk[g*4+3] = m4.w;
    }
    int c = 0;
#pragma unroll
    for (int i = 0; i < 16; ++i) c += (mk[i] != 0) ? 1 : 0;
    int v = c;
    sc[t] = v;
    __syncthreads();
    for (int off = 1; off < 1024; off <<= 1) {       // Hillis-Steele scan
        int u = (t >= off) ? sc[t - off] : 0;
        __syncthreads();
        v += u; sc[t] = v;
        __syncthreads();
    }
    int b  = v - c;
    int zb = base - b;
#pragma unroll
    for (int i = 0; i < 16; ++i) {
        int r = base + i;
        if (mk[i] != 0) idx[b++] = r; else zidx[zb++] = r;
    }
    if (t == 1023) count[0] = v;
}

// ---- gather+zfill: blocks 0..2047 gather-convert active rows of x into xb;
//      blocks 2048..3071 zero FULL masked rows of out (float4, contiguous). ---
__global__ __launch_bounds__(256) void gather_zfill_kernel(
    const float* __restrict__ x, const int* __restrict__ idx,
    const int* __restrict__ zidx, const int* __restrict__ count,
    __bf16* __restrict__ xb, float* __restrict__ out) {
    const int t = threadIdx.x;
    if (blockIdx.x < 2048) {
        const int cnt = count[0];
        for (int j = blockIdx.x; j < cnt; j += 2048) {
            const int row = idx[j];
            float4 v = reinterpret_cast<const float4*>(x + (size_t)row * K_DIM)[t];
            bf16x4 o;
            o[0] = (__bf16)v.x; o[1] = (__bf16)v.y; o[2] = (__bf16)v.z; o[3] = (__bf16)v.w;
            reinterpret_cast<bf16x4*>(xb + (size_t)j * K_DIM)[t] = o;
        }
    } else {
        const int nz = N_ROWS - count[0];
        const int zb = blockIdx.x - 2048;            // 0..1023
        const float4 zf = make_float4(0.f, 0.f, 0.f, 0.f);
        for (int i = zb; i < nz; i += 1024) {        // one full row per block-iter
            const int row = zidx[i];
            float4* p = reinterpret_cast<float4*>(out + (size_t)row * N_OUT);
#pragma unroll
            for (int u = 0; u < 4; ++u)              // 256 thr x 4 float4 = 16 KB
                p[u * 256 + t] = zf;
        }
    }
}

// ---------------- PURE compacted 128x128 m97-structure bf16 MFMA GEMM ---------
// Attribution round: EXACT R1 structure + R1 dispatch mapping (tn fast, tm
// slow, no XCD logic, no role mixing). Only deltas vs R1's verified 725-TF
// heavy path: A base is the compacted xb, epilogue scatters via idx.
// Blocks with tm >= aT exit immediately (grid fixed at 4096 for capture).

#define GLL(SRC, DSTOFF)                                                       \
    __builtin_amdgcn_global_load_lds(                                          \
        (const __attribute__((address_space(1))) void*)(SRC),                  \
        (__attribute__((address_space(3))) void*)(ldsc + (DSTOFF)), 16, 0, 0)

__global__ __launch_bounds__(256) void gemm_kernel(
    const __bf16* __restrict__ A,      // compacted active rows
    const __bf16* __restrict__ B,
    const float*  __restrict__ bias,
    const int*    __restrict__ idx,
    const int*    __restrict__ count,
    float*        __restrict__ out)
{
    __shared__ short lds_all[8192];    // 16 KB: A [128][32] @0, B [128][32] @8192B

    const int cnt = count[0];
    const int aT  = (cnt + 127) >> 7;  // active row-tiles of 128
    const int tn  = blockIdx.x & 31;   // fast axis (R1 mapping)
    const int tm  = blockIdx.x >> 5;   // 0..127
    if (tm >= aT) return;

    const int t  = threadIdx.x;
    const int l  = t & 63;
    const int w  = t >> 6;             // wave 0..3
    const int wm = w >> 1;             // 0..1
    const int wn = w & 1;              // 0..1

    const int m0 = tm * 128;           // base in COMPACTED row space
    const int n0 = tn * 128;

    // R1-style coalesced staging: thread t stages row (t>>2), k8 = (t&3)*8.
    const int srow = t >> 2;
    const int sk8  = (t & 3) * 8;
    const __bf16* pA0 = A + (size_t)(m0 + srow) * K_DIM + sk8;
    const __bf16* pA1 = pA0 + (size_t)64 * K_DIM;
    const __bf16* pB0 = B + (size_t)(n0 + srow) * K_DIM + sk8;
    const __bf16* pB1 = pB0 + (size_t)64 * K_DIM;
    char* ldsc = (char*)lds_all;

    const int lr = l & 15;
    const int lk = (l >> 4) * 8;

    f32x4 acc[4][4] = {};

    for (int k0 = 0; k0 < K_DIM; k0 += 32) {
        GLL(pA0 + k0, t * 16);
        GLL(pA1 + k0, 4096 + t * 16);
        GLL(pB0 + k0, 8192 + t * 16);
        GLL(pB1 + k0, 12288 + t * 16);
        __syncthreads();

        short8 af[4], bf[4];
#pragma unroll
        for (int mi = 0; mi < 4; ++mi)
            af[mi] = *(const short8*)(lds_all + (wm*64 + mi*16 + lr)*32 + lk);
#pragma unroll
        for (int ni = 0; ni < 4; ++ni)
            bf[ni] = *(const short8*)(lds_all + 4096 + (wn*64 + ni*16 + lr)*32 + lk);

#pragma unroll
        for (int mi = 0; mi < 4; ++mi)
#pragma unroll
            for (int ni = 0; ni < 4; ++ni)
                acc[mi][ni] = __builtin_amdgcn_mfma_f32_16x16x32_bf16(
                    af[mi], bf[ni], acc[mi][ni], 0, 0, 0);
        __syncthreads();
    }

    // Epilogue: bias add, scatter to original rows, guard padded slots.
    const int lq = l >> 4;
    float bv[4];
#pragma unroll
    for (int ni = 0; ni < 4; ++ni) bv[ni] = bias[n0 + wn*64 + ni*16 + lr];

#pragma unroll
    for (int mi = 0; mi < 4; ++mi) {
        const int slot0 = m0 + wm*64 + mi*16 + lq*4;
        int rowid[4]; bool val[4];
#pragma unroll
        for (int r = 0; r < 4; ++r) {
            const int s = slot0 + r;
            val[r] = (s < cnt);
            rowid[r] = val[r] ? idx[s] : 0;
        }
#pragma unroll
        for (int ni = 0; ni < 4; ++ni) {
            const int cc = n0 + wn*64 + ni*16 + lr;
#pragma unroll
            for (int r = 0; r < 4; ++r)
                if (val[r]) out[(size_t)rowid[r] * N_OUT + cc] = acc[mi][ni][r] + bv[ni];
        }
    }
}

// ---------------- naive fp32 fallback (only if ws too small) ------------------
__global__ void naive_kernel(const float* __restrict__ x, const float* __restrict__ W,
                             const float* __restrict__ bias, const int* __restrict__ amask,
                             float* __restrict__ out) {
    int c = blockIdx.x * blockDim.x + threadIdx.x;
    int r = blockIdx.y;
    if (c >= N_OUT) return;
    if (amask[r] == 0) { out[(size_t)r * N_OUT + c] = 0.0f; return; }
    const float* xr = x + (size_t)r * K_DIM;
    const float* wr = W + (size_t)c * K_DIM;
    float s = 0.0f;
    for (int k = 0; k < K_DIM; ++k) s += xr[k] * wr[k];
    out[(size_t)r * N_OUT + c] = s + bias[c];
}

extern "C" void kernel_launch(void* const* d_in, const int* in_sizes, int n_in,
                              void* d_out, int out_size, void* d_ws, size_t ws_size,
                              hipStream_t stream) {
    const float* x     = (const float*)d_in[0];
    const int*   amask = (const int*)d_in[1];
    const float* W     = (const float*)d_in[2];
    const float* bias  = (const float*)d_in[3];
    float*       out   = (float*)d_out;

    const size_t xb_bytes = (size_t)N_ROWS * K_DIM * 2;   // 32 MB
    const size_t wb_bytes = (size_t)N_OUT  * K_DIM * 2;   //  8 MB
    const size_t idx_bytes = (size_t)N_ROWS * 4;          // 64 KB
    const size_t need = xb_bytes + wb_bytes + 2 * idx_bytes + 256;

    if (ws_size < need) {
        dim3 g((N_OUT + 255) / 256, N_ROWS);
        naive_kernel<<<g, 256, 0, stream>>>(x, W, bias, amask, out);
        return;
    }

    __bf16* xb   = (__bf16*)d_ws;
    __bf16* wb   = (__bf16*)((char*)d_ws + xb_bytes);
    int*    idx  = (int*)((char*)d_ws + xb_bytes + wb_bytes);
    int*    zidx = idx + N_ROWS;
    int*    cnt  = zidx + N_ROWS;

    prep_kernel<<<1025, 1024, 0, stream>>>(amask, W, idx, zidx, cnt, wb);
    gather_zfill_kernel<<<3072, 256, 0, stream>>>(x, idx, zidx, cnt, xb, out);
    gemm_kernel<<<4096, 256, 0, stream>>>(xb, wb, bias, idx, cnt, out);
}